// Round 2
// baseline (468.559 us; speedup 1.0000x reference)
//
#include <hip/hip_runtime.h>
#include <hip/hip_bf16.h>

typedef __bf16 bf16x8 __attribute__((ext_vector_type(8)));
typedef __bf16 bf16x4 __attribute__((ext_vector_type(4)));
typedef float  f32x4  __attribute__((ext_vector_type(4)));

// tanh(x) = 1 - 2/(exp(2x)+1); native v_exp + v_rcp (no IEEE div expansion).
__device__ __forceinline__ float fast_tanh(float x) {
    float e = __expf(2.0f * x);
    float r = __builtin_amdgcn_rcpf(e + 1.0f);
    return __builtin_fmaf(-2.0f, r, 1.0f);
}

// Convert fp32 weights to bf16, TRANSPOSED to [n][k] (MFMA A-operand layout).
__global__ void prep_weights(const float* __restrict__ W1,
                             const float* __restrict__ W2,
                             const float* __restrict__ W3,
                             __bf16* __restrict__ w1t,   // [256][64]
                             __bf16* __restrict__ w2t,   // [256][256]
                             __bf16* __restrict__ w3t) { // [64][256]
    int idx = blockIdx.x * blockDim.x + threadIdx.x;
    if (idx < 64 * 256) {                 // W1 [k=64][n=256] -> W1T[n][k]
        int n = idx >> 6, k = idx & 63;
        w1t[idx] = (__bf16)W1[k * 256 + n];
    }
    int i2 = idx - 64 * 256;
    if (i2 >= 0 && i2 < 256 * 256) {      // W2 [k=256][n=256] -> W2T[n][k]
        int n = i2 >> 8, k = i2 & 255;
        w2t[i2] = (__bf16)W2[k * 256 + n];
    }
    int i3 = idx - 64 * 256 - 256 * 256;  // W3 [k=256][n=64] -> W3T[n][k]
    if (i3 >= 0 && i3 < 64 * 256) {
        int n = i3 >> 8, k = i3 & 255;
        w3t[i3] = (__bf16)W3[k * 64 + n];
    }
}

// W31 = W3 @ W1 (fp32 compute, single bf16 rounding), stored [n][k].
// c31 = b3 @ W1 (fp32).  Enables y-space recurrence: y' = y + s*(h2@W31 + c31).
__global__ void prep_w31(const float* __restrict__ W1,
                         const float* __restrict__ W3,
                         const float* __restrict__ b3,
                         __bf16* __restrict__ w31t,   // [n=256][k=256]
                         float*  __restrict__ c31) {  // [256]
    int idx = blockIdx.x * blockDim.x + threadIdx.x;  // 65536
    int k = idx & 255, n = idx >> 8;
    float acc = 0.f;
    #pragma unroll 8
    for (int j = 0; j < 64; ++j) acc += W3[k * 64 + j] * W1[j * 256 + n];
    w31t[n * 256 + k] = (__bf16)acc;
    if (idx < 256) {
        float a = 0.f;
        for (int j = 0; j < 64; ++j) a += b3[j] * W1[j * 256 + idx];
        c31[idx] = a;
    }
}

// One block = 16 batch rows for ALL time steps. 512 threads = 8 waves.
// Recurrence in y-space (y = x@W1, fp32 persistent REGISTERS):
//   P1: h2 = tanh(h1@W2 + b2)                      [barrier]
//   P2: y += s*(h2@W31 + c31); h1 = tanh(y+b1)
//       dx partials = h2@W3 (split-K over 8 waves) [barrier]
//   store: x += s*(dx0+dx1+b3)  (x fp32 in store-lane registers)
// => 2 barriers/step (was 3), no idle waves, y/x never round-trip LDS.
__global__ __launch_bounds__(512, 2)
void ode_kernel(const float* __restrict__ x0,
                const float* __restrict__ b1,
                const float* __restrict__ b2,
                const float* __restrict__ b3,
                const float* __restrict__ dt_scale,
                const int*   __restrict__ num_steps,
                const __bf16* __restrict__ w1t,
                const __bf16* __restrict__ w2t,
                const __bf16* __restrict__ w3t,
                const __bf16* __restrict__ w31t,
                const float*  __restrict__ c31,
                float* __restrict__ out) {
    __shared__ __align__(16) __bf16 h1[16][264];     // stride 132 words
    __shared__ __align__(16) __bf16 h2[16][264];
    __shared__ __align__(16) float  dxp[2][16][68];  // split-K dx partials

    const int tid  = threadIdx.x;
    const int wave = tid >> 6;
    const int lane = tid & 63;
    const int q    = lane >> 4;
    const int c    = lane & 15;
    const int row0 = blockIdx.x * 16;

    const int tileN = (wave & 3) * 16;   // GEMM3 output n-tile
    const int khalf = wave >> 2;         // GEMM3 k-half

    const float scale = dt_scale[0] * 0.01f;
    const int   nT    = num_steps[0];

    // ---- bias fragments ----
    f32x4 b1v4[2], b2v4[2], c31v[2];
    #pragma unroll
    for (int nt = 0; nt < 2; ++nt) {
        b1v4[nt] = *(const f32x4*)(b1  + wave * 32 + nt * 16 + q * 4);
        b2v4[nt] = *(const f32x4*)(b2  + wave * 32 + nt * 16 + q * 4);
        c31v[nt] = *(const f32x4*)(c31 + wave * 32 + nt * 16 + q * 4);
    }

    // ---- store-lane state: x in registers ----
    const int mio = tid >> 5, sio = (tid & 31) * 2;
    float* outp = out + ((size_t)(row0 + mio) * 201) * 64 + sio;
    float2 xv = *(const float2*)(x0 + (size_t)(row0 + mio) * 64 + sio);
    const float2 b3v = {b3[sio], b3[sio + 1]};
    *(float2*)outp = xv;   // t = 0 slice
    outp += 64;

    // ---- init: y0 = x0 @ W1 (fp32 MFMA accum), h1 = tanh(y0+b1) ----
    f32x4 yv[2];
    {
        bf16x8 xf[2];
        #pragma unroll
        for (int kt = 0; kt < 2; ++kt) {
            const float* px = x0 + (size_t)(row0 + c) * 64 + kt * 32 + q * 8;
            float4 lo = *(const float4*)(px);
            float4 hi = *(const float4*)(px + 4);
            xf[kt][0] = (__bf16)lo.x; xf[kt][1] = (__bf16)lo.y;
            xf[kt][2] = (__bf16)lo.z; xf[kt][3] = (__bf16)lo.w;
            xf[kt][4] = (__bf16)hi.x; xf[kt][5] = (__bf16)hi.y;
            xf[kt][6] = (__bf16)hi.z; xf[kt][7] = (__bf16)hi.w;
        }
        yv[0] = (f32x4){0.f, 0.f, 0.f, 0.f};
        yv[1] = (f32x4){0.f, 0.f, 0.f, 0.f};
        #pragma unroll
        for (int kt = 0; kt < 2; ++kt)
            #pragma unroll
            for (int nt = 0; nt < 2; ++nt) {
                int n = wave * 32 + nt * 16 + c;
                bf16x8 w1f = *(const bf16x8*)(w1t + n * 64 + kt * 32 + q * 8);
                yv[nt] = __builtin_amdgcn_mfma_f32_16x16x32_bf16(w1f, xf[kt], yv[nt], 0, 0, 0);
            }
        #pragma unroll
        for (int nt = 0; nt < 2; ++nt) {
            bf16x4 o;
            #pragma unroll
            for (int r = 0; r < 4; ++r) o[r] = (__bf16)fast_tanh(yv[nt][r] + b1v4[nt][r]);
            *(bf16x4*)(&h1[c][wave * 32 + nt * 16 + q * 4]) = o;
        }
    }

    // ---- persistent weight fragments (A-operand layout [n][k]) ----
    bf16x8 w2f[8][2], w31f[8][2];
    #pragma unroll
    for (int kt = 0; kt < 8; ++kt)
        #pragma unroll
        for (int nt = 0; nt < 2; ++nt) {
            int n = wave * 32 + nt * 16 + c;
            w2f[kt][nt]  = *(const bf16x8*)(w2t  + n * 256 + kt * 32 + q * 8);
            w31f[kt][nt] = *(const bf16x8*)(w31t + n * 256 + kt * 32 + q * 8);
        }
    bf16x8 w3f[4];
    #pragma unroll
    for (int kk = 0; kk < 4; ++kk) {
        int n = tileN + c;
        w3f[kk] = *(const bf16x8*)(w3t + n * 256 + (khalf * 4 + kk) * 32 + q * 8);
    }

    __syncthreads();

    for (int t = 0; t < nT; ++t) {
        // ---- P1: h2 = tanh(h1 @ W2 + b2) ----
        {
            f32x4 acc[2]  = {b2v4[0], b2v4[1]};
            f32x4 accB[2] = {(f32x4){0,0,0,0}, (f32x4){0,0,0,0}};
            #pragma unroll
            for (int kt = 0; kt < 4; ++kt) {
                bf16x8 a0 = *(const bf16x8*)(&h1[c][kt * 32 + q * 8]);
                bf16x8 a1 = *(const bf16x8*)(&h1[c][(kt + 4) * 32 + q * 8]);
                acc[0]  = __builtin_amdgcn_mfma_f32_16x16x32_bf16(w2f[kt][0],     a0, acc[0],  0, 0, 0);
                acc[1]  = __builtin_amdgcn_mfma_f32_16x16x32_bf16(w2f[kt][1],     a0, acc[1],  0, 0, 0);
                accB[0] = __builtin_amdgcn_mfma_f32_16x16x32_bf16(w2f[kt + 4][0], a1, accB[0], 0, 0, 0);
                accB[1] = __builtin_amdgcn_mfma_f32_16x16x32_bf16(w2f[kt + 4][1], a1, accB[1], 0, 0, 0);
            }
            #pragma unroll
            for (int nt = 0; nt < 2; ++nt) {
                f32x4 s = acc[nt] + accB[nt];
                bf16x4 o;
                #pragma unroll
                for (int r = 0; r < 4; ++r) o[r] = (__bf16)fast_tanh(s[r]);
                *(bf16x4*)(&h2[c][wave * 32 + nt * 16 + q * 4]) = o;
            }
        }
        __syncthreads();   // B1: h2 ready

        // ---- P2: y += s*(h2@W31 + c31); h1 = tanh(y+b1); dx partial = h2@W3 ----
        {
            f32x4 accY[2]  = {c31v[0], c31v[1]};
            f32x4 accYB[2] = {(f32x4){0,0,0,0}, (f32x4){0,0,0,0}};
            f32x4 accX     = (f32x4){0, 0, 0, 0};

            bf16x8 f0 = *(const bf16x8*)(&h2[c][0 * 32 + q * 8]);
            bf16x8 f1 = *(const bf16x8*)(&h2[c][1 * 32 + q * 8]);
            bf16x8 f2 = *(const bf16x8*)(&h2[c][2 * 32 + q * 8]);
            bf16x8 f3 = *(const bf16x8*)(&h2[c][3 * 32 + q * 8]);
            accY[0]  = __builtin_amdgcn_mfma_f32_16x16x32_bf16(w31f[0][0], f0, accY[0],  0, 0, 0);
            accY[1]  = __builtin_amdgcn_mfma_f32_16x16x32_bf16(w31f[0][1], f0, accY[1],  0, 0, 0);
            accYB[0] = __builtin_amdgcn_mfma_f32_16x16x32_bf16(w31f[1][0], f1, accYB[0], 0, 0, 0);
            accYB[1] = __builtin_amdgcn_mfma_f32_16x16x32_bf16(w31f[1][1], f1, accYB[1], 0, 0, 0);
            accY[0]  = __builtin_amdgcn_mfma_f32_16x16x32_bf16(w31f[2][0], f2, accY[0],  0, 0, 0);
            accY[1]  = __builtin_amdgcn_mfma_f32_16x16x32_bf16(w31f[2][1], f2, accY[1],  0, 0, 0);
            accYB[0] = __builtin_amdgcn_mfma_f32_16x16x32_bf16(w31f[3][0], f3, accYB[0], 0, 0, 0);
            accYB[1] = __builtin_amdgcn_mfma_f32_16x16x32_bf16(w31f[3][1], f3, accYB[1], 0, 0, 0);
            if (khalf == 0) {
                accX = __builtin_amdgcn_mfma_f32_16x16x32_bf16(w3f[0], f0, accX, 0, 0, 0);
                accX = __builtin_amdgcn_mfma_f32_16x16x32_bf16(w3f[1], f1, accX, 0, 0, 0);
                accX = __builtin_amdgcn_mfma_f32_16x16x32_bf16(w3f[2], f2, accX, 0, 0, 0);
                accX = __builtin_amdgcn_mfma_f32_16x16x32_bf16(w3f[3], f3, accX, 0, 0, 0);
            }
            bf16x8 f4 = *(const bf16x8*)(&h2[c][4 * 32 + q * 8]);
            bf16x8 f5 = *(const bf16x8*)(&h2[c][5 * 32 + q * 8]);
            bf16x8 f6 = *(const bf16x8*)(&h2[c][6 * 32 + q * 8]);
            bf16x8 f7 = *(const bf16x8*)(&h2[c][7 * 32 + q * 8]);
            accY[0]  = __builtin_amdgcn_mfma_f32_16x16x32_bf16(w31f[4][0], f4, accY[0],  0, 0, 0);
            accY[1]  = __builtin_amdgcn_mfma_f32_16x16x32_bf16(w31f[4][1], f4, accY[1],  0, 0, 0);
            accYB[0] = __builtin_amdgcn_mfma_f32_16x16x32_bf16(w31f[5][0], f5, accYB[0], 0, 0, 0);
            accYB[1] = __builtin_amdgcn_mfma_f32_16x16x32_bf16(w31f[5][1], f5, accYB[1], 0, 0, 0);
            accY[0]  = __builtin_amdgcn_mfma_f32_16x16x32_bf16(w31f[6][0], f6, accY[0],  0, 0, 0);
            accY[1]  = __builtin_amdgcn_mfma_f32_16x16x32_bf16(w31f[6][1], f6, accY[1],  0, 0, 0);
            accYB[0] = __builtin_amdgcn_mfma_f32_16x16x32_bf16(w31f[7][0], f7, accYB[0], 0, 0, 0);
            accYB[1] = __builtin_amdgcn_mfma_f32_16x16x32_bf16(w31f[7][1], f7, accYB[1], 0, 0, 0);
            if (khalf == 1) {
                accX = __builtin_amdgcn_mfma_f32_16x16x32_bf16(w3f[0], f4, accX, 0, 0, 0);
                accX = __builtin_amdgcn_mfma_f32_16x16x32_bf16(w3f[1], f5, accX, 0, 0, 0);
                accX = __builtin_amdgcn_mfma_f32_16x16x32_bf16(w3f[2], f6, accX, 0, 0, 0);
                accX = __builtin_amdgcn_mfma_f32_16x16x32_bf16(w3f[3], f7, accX, 0, 0, 0);
            }

            #pragma unroll
            for (int nt = 0; nt < 2; ++nt) {
                yv[nt] += (accY[nt] + accYB[nt]) * scale;
                bf16x4 o;
                #pragma unroll
                for (int r = 0; r < 4; ++r) o[r] = (__bf16)fast_tanh(yv[nt][r] + b1v4[nt][r]);
                *(bf16x4*)(&h1[c][wave * 32 + nt * 16 + q * 4]) = o;
            }
            *(f32x4*)(&dxp[khalf][c][tileN + q * 4]) = accX;
        }
        __syncthreads();   // B2: h1, dxp ready

        // ---- trajectory store: x += s*(dx0+dx1+b3); overlaps next P1 ----
        {
            float2 d0 = *(const float2*)(&dxp[0][mio][sio]);
            float2 d1 = *(const float2*)(&dxp[1][mio][sio]);
            xv.x += scale * (d0.x + d1.x + b3v.x);
            xv.y += scale * (d0.y + d1.y + b3v.y);
            *(float2*)outp = xv;
            outp += 64;
        }
    }
}

extern "C" void kernel_launch(void* const* d_in, const int* in_sizes, int n_in,
                              void* d_out, int out_size, void* d_ws, size_t ws_size,
                              hipStream_t stream) {
    const float* x0 = (const float*)d_in[0];
    const float* W1 = (const float*)d_in[1];
    const float* b1 = (const float*)d_in[2];
    const float* W2 = (const float*)d_in[3];
    const float* b2 = (const float*)d_in[4];
    const float* W3 = (const float*)d_in[5];
    const float* b3 = (const float*)d_in[6];
    const float* dt = (const float*)d_in[7];
    const int*   ns = (const int*)d_in[8];

    __bf16* w1t  = (__bf16*)d_ws;          // 16384 bf16
    __bf16* w2t  = w1t + 64 * 256;         // 65536 bf16
    __bf16* w3t  = w2t + 256 * 256;        // 16384 bf16
    __bf16* w31t = w3t + 64 * 256;         // 65536 bf16
    float*  c31  = (float*)(w31t + 256 * 256);  // 256 f32

    prep_weights<<<384, 256, 0, stream>>>(W1, W2, W3, w1t, w2t, w3t);
    prep_w31<<<256, 256, 0, stream>>>(W1, W3, b3, w31t, c31);

    int rows = in_sizes[0] / 64;           // 4096
    ode_kernel<<<rows / 16, 512, 0, stream>>>(x0, b1, b2, b3, dt, ns,
                                              w1t, w2t, w3t, w31t, c31,
                                              (float*)d_out);
}

// Round 3
// 443.360 us; speedup vs baseline: 1.0568x; 1.0568x over previous
//
#include <hip/hip_runtime.h>
#include <hip/hip_bf16.h>

typedef __bf16 bf16x8 __attribute__((ext_vector_type(8)));
typedef __bf16 bf16x4 __attribute__((ext_vector_type(4)));
typedef float  f32x4  __attribute__((ext_vector_type(4)));

// tanh(x) = 1 - 2/(exp(2x)+1); native v_exp + v_rcp (no IEEE div expansion).
__device__ __forceinline__ float fast_tanh(float x) {
    float e = __expf(2.0f * x);
    float r = __builtin_amdgcn_rcpf(e + 1.0f);
    return __builtin_fmaf(-2.0f, r, 1.0f);
}

// Convert fp32 weights to bf16, TRANSPOSED to [n][k]: each lane's MFMA
// A-operand fragment (8 consecutive k at fixed n) is one contiguous 16B load.
__global__ void prep_weights(const float* __restrict__ W1,
                             const float* __restrict__ W2,
                             const float* __restrict__ W3,
                             __bf16* __restrict__ w1t,   // [256][64]
                             __bf16* __restrict__ w2t,   // [256][256]
                             __bf16* __restrict__ w3t) { // [64][256]
    int idx = blockIdx.x * blockDim.x + threadIdx.x;
    if (idx < 64 * 256) {                 // W1 [k=64][n=256] -> W1T[n][k]
        int n = idx >> 6, k = idx & 63;
        w1t[idx] = (__bf16)W1[k * 256 + n];
    }
    int i2 = idx - 64 * 256;
    if (i2 >= 0 && i2 < 256 * 256) {      // W2 [k=256][n=256] -> W2T[n][k]
        int n = i2 >> 8, k = i2 & 255;
        w2t[i2] = (__bf16)W2[k * 256 + n];
    }
    int i3 = idx - 64 * 256 - 256 * 256;  // W3 [k=256][n=64] -> W3T[n][k]
    if (i3 >= 0 && i3 < 64 * 256) {
        int n = i3 >> 8, k = i3 & 255;
        w3t[i3] = (__bf16)W3[k * 64 + n];
    }
}

// One block = 16 batch rows for ALL time steps. 512 threads = 8 waves.
// OPERAND-SWAPPED MFMA: A = weight (W^T[n][k]), B = activation (h[m][k]).
// h1/h2 live in flat [16][256] bf16 with XOR bank-swizzle: element offset
// within a row is XORed with (c&7)<<3 (flips 16B-granule bits). Read slot
// = ((4kt+q) ^ (c&7)) mod 8 -> exactly 2 lanes/slot = conflict-free (m136).
// Same XOR on write and read; row base untouched -> bijective, bit-identical.
__global__ __launch_bounds__(512, 2)
void ode_kernel(const float* __restrict__ x0,
                const float* __restrict__ b1,
                const float* __restrict__ b2,
                const float* __restrict__ b3,
                const float* __restrict__ dt_scale,
                const int*   __restrict__ num_steps,
                const __bf16* __restrict__ w1t,
                const __bf16* __restrict__ w2t,
                const __bf16* __restrict__ w3t,
                float* __restrict__ out) {
    __shared__ float  xs[16][68];    // fp32 state; 272B stride = 17 granules, clean
    __shared__ __bf16 xb[16][72];    // bf16 state copy; 144B = 9 granules, clean
    __shared__ __align__(16) __bf16 h1[16 * 256];   // swizzled, 512B row stride
    __shared__ __align__(16) __bf16 h2[16 * 256];

    const int tid  = threadIdx.x;
    const int wave = tid >> 6;
    const int lane = tid & 63;
    const int q    = lane >> 4;      // quad: k-block of frags / n-subblock of D
    const int c    = lane & 15;      // n for A-frag(weight), m(batch row) for B-frag & D
    const int cx8  = (c & 7) << 3;   // h1/h2 swizzle term (element units)
    const int row0 = blockIdx.x * 16;

    const float scale = dt_scale[0] * 0.01f;   // dt_scale * DT
    const int   nT    = num_steps[0];

    // ---- one-time weight fragment loads (A-operand layout, [n][k]) ----
    bf16x8 w1f[2][2];                 // [kt][nt], n = wave*32 + nt*16 + c
    #pragma unroll
    for (int kt = 0; kt < 2; ++kt)
        #pragma unroll
        for (int nt = 0; nt < 2; ++nt) {
            int n = wave * 32 + nt * 16 + c;
            w1f[kt][nt] = *(const bf16x8*)(w1t + n * 64 + kt * 32 + q * 8);
        }
    bf16x8 w2f[8][2];
    #pragma unroll
    for (int kt = 0; kt < 8; ++kt)
        #pragma unroll
        for (int nt = 0; nt < 2; ++nt) {
            int n = wave * 32 + nt * 16 + c;
            w2f[kt][nt] = *(const bf16x8*)(w2t + n * 256 + kt * 32 + q * 8);
        }
    bf16x8 w3f[8];
    f32x4  b3v4 = (f32x4){0.f, 0.f, 0.f, 0.f};
    if (wave < 4) {
        int n = wave * 16 + c;
        #pragma unroll
        for (int kt = 0; kt < 8; ++kt)
            w3f[kt] = *(const bf16x8*)(w3t + n * 256 + kt * 32 + q * 8);
        b3v4 = *(const f32x4*)(b3 + wave * 16 + q * 4);   // n = w*16 + q*4 + r
    }
    f32x4 b1v4[2], b2v4[2];
    #pragma unroll
    for (int nt = 0; nt < 2; ++nt) {
        b1v4[nt] = *(const f32x4*)(b1 + wave * 32 + nt * 16 + q * 4);
        b2v4[nt] = *(const f32x4*)(b2 + wave * 32 + nt * 16 + q * 4);
    }

    // ---- load x0 into LDS state, emit t=0 trajectory slice ----
    const int mio = tid >> 5, sio = (tid & 31) * 2;
    float* outp = out + ((size_t)(row0 + mio) * 201) * 64 + sio;
    {
        const float2 v = *(const float2*)(x0 + (size_t)(row0 + mio) * 64 + sio);
        xs[mio][sio]     = v.x;  xs[mio][sio + 1] = v.y;
        xb[mio][sio]     = (__bf16)v.x;
        xb[mio][sio + 1] = (__bf16)v.y;
        *(float2*)outp = v;
        outp += 64;
    }
    __syncthreads();

    for (int t = 0; t < nT; ++t) {
        // GEMM1: h1 = tanh(x @ W1 + b1)   D[n][m], lane: m=c, n=base+q*4+r
        {
            f32x4 acc[2] = {b1v4[0], b1v4[1]};
            #pragma unroll
            for (int kt = 0; kt < 2; ++kt) {
                bf16x8 a = *(const bf16x8*)(&xb[c][kt * 32 + q * 8]);
                acc[0] = __builtin_amdgcn_mfma_f32_16x16x32_bf16(w1f[kt][0], a, acc[0], 0, 0, 0);
                acc[1] = __builtin_amdgcn_mfma_f32_16x16x32_bf16(w1f[kt][1], a, acc[1], 0, 0, 0);
            }
            #pragma unroll
            for (int nt = 0; nt < 2; ++nt) {
                bf16x4 o;
                #pragma unroll
                for (int r = 0; r < 4; ++r) o[r] = (__bf16)fast_tanh(acc[nt][r]);
                *(bf16x4*)(&h1[c * 256 + ((wave * 32 + nt * 16 + q * 4) ^ cx8)]) = o;
            }
        }
        __syncthreads();

        // GEMM2: h2 = tanh(h1 @ W2 + b2); two independent 4-deep acc chains
        {
            f32x4 acc[2]  = {b2v4[0], b2v4[1]};
            f32x4 accB[2] = {(f32x4){0,0,0,0}, (f32x4){0,0,0,0}};
            #pragma unroll
            for (int kt = 0; kt < 4; ++kt) {
                bf16x8 a0 = *(const bf16x8*)(&h1[c * 256 + ((kt * 32 + q * 8) ^ cx8)]);
                bf16x8 a1 = *(const bf16x8*)(&h1[c * 256 + (((kt + 4) * 32 + q * 8) ^ cx8)]);
                acc[0]  = __builtin_amdgcn_mfma_f32_16x16x32_bf16(w2f[kt][0],     a0, acc[0],  0, 0, 0);
                acc[1]  = __builtin_amdgcn_mfma_f32_16x16x32_bf16(w2f[kt][1],     a0, acc[1],  0, 0, 0);
                accB[0] = __builtin_amdgcn_mfma_f32_16x16x32_bf16(w2f[kt + 4][0], a1, accB[0], 0, 0, 0);
                accB[1] = __builtin_amdgcn_mfma_f32_16x16x32_bf16(w2f[kt + 4][1], a1, accB[1], 0, 0, 0);
            }
            #pragma unroll
            for (int nt = 0; nt < 2; ++nt) {
                f32x4 s = acc[nt] + accB[nt];
                bf16x4 o;
                #pragma unroll
                for (int r = 0; r < 4; ++r) o[r] = (__bf16)fast_tanh(s[r]);
                *(bf16x4*)(&h2[c * 256 + ((wave * 32 + nt * 16 + q * 4) ^ cx8)]) = o;
            }
        }
        __syncthreads();

        // GEMM3: dx = h2 @ W3 + b3; x += dx*scale  (waves 0..3; vectorized RMW)
        if (wave < 4) {
            f32x4 acc  = b3v4;
            f32x4 accB = (f32x4){0, 0, 0, 0};
            #pragma unroll
            for (int kt = 0; kt < 4; ++kt) {
                bf16x8 a0 = *(const bf16x8*)(&h2[c * 256 + ((kt * 32 + q * 8) ^ cx8)]);
                bf16x8 a1 = *(const bf16x8*)(&h2[c * 256 + (((kt + 4) * 32 + q * 8) ^ cx8)]);
                acc  = __builtin_amdgcn_mfma_f32_16x16x32_bf16(w3f[kt],     a0, acc,  0, 0, 0);
                accB = __builtin_amdgcn_mfma_f32_16x16x32_bf16(w3f[kt + 4], a1, accB, 0, 0, 0);
            }
            acc += accB;
            f32x4 xv = *(f32x4*)(&xs[c][wave * 16 + q * 4]);
            xv += acc * scale;
            *(f32x4*)(&xs[c][wave * 16 + q * 4]) = xv;
            bf16x4 xbv;
            #pragma unroll
            for (int r = 0; r < 4; ++r) xbv[r] = (__bf16)xv[r];
            *(bf16x4*)(&xb[c][wave * 16 + q * 4]) = xbv;
        }
        __syncthreads();

        // trajectory store (coalesced float2); overlaps next GEMM1
        {
            float2 v = *(const float2*)(&xs[mio][sio]);
            *(float2*)outp = v;
            outp += 64;
        }
    }
}

extern "C" void kernel_launch(void* const* d_in, const int* in_sizes, int n_in,
                              void* d_out, int out_size, void* d_ws, size_t ws_size,
                              hipStream_t stream) {
    const float* x0 = (const float*)d_in[0];
    const float* W1 = (const float*)d_in[1];
    const float* b1 = (const float*)d_in[2];
    const float* W2 = (const float*)d_in[3];
    const float* b2 = (const float*)d_in[4];
    const float* W3 = (const float*)d_in[5];
    const float* b3 = (const float*)d_in[6];
    const float* dt = (const float*)d_in[7];
    const int*   ns = (const int*)d_in[8];

    __bf16* w1t = (__bf16*)d_ws;           // 16384 bf16
    __bf16* w2t = w1t + 64 * 256;          // 65536 bf16
    __bf16* w3t = w2t + 256 * 256;         // 16384 bf16

    prep_weights<<<384, 256, 0, stream>>>(W1, W2, W3, w1t, w2t, w3t);

    int rows = in_sizes[0] / 64;           // 4096
    ode_kernel<<<rows / 16, 512, 0, stream>>>(x0, b1, b2, b3, dt, ns,
                                              w1t, w2t, w3t, (float*)d_out);
}